// Round 6
// baseline (636.341 us; speedup 1.0000x reference)
//
#include <hip/hip_runtime.h>

// AttentionBasedNN: persistent mega-kernel, round-10.
// VEC=1280, HID=128, B=4, S=256, fp32 (no fp32 MFMA on CDNA4 -> vector ALU).
//
// Coherence scheme (proven rounds 6-9): intermediates are WRITE-ONCE
// versioned buffers; stores bypass L1/L2 (sc0 sc1 -> coherence point),
// loads normal cached; grid barrier = fence-free monotonic tree counters.
//
// Round-9 post-mortem: VALUBusy stuck at 26% -> residual is phase-tail +
// barrier overhead (~12us x 23) + CU load imbalance (320-task phases on
// 512 blocks -> busiest CU does 2x). Round-10:
//  (1) FUSE scores+PV+LN into one phase: attn rows stay in LDS, PV = 2
//      dot-rows vs Xin (L2-shared), LN in-register. -2 barriers/layer,
//      -attn/-Yraw traffic, kills the worst-imbalanced GEMM phase.
//  (2) Balance FC1 (512 tasks, BM=32) and FC2 (640 tasks, BM=32 via
//      dynamic ticket queue -- monotonic atomic, fence-free).
//  (3) Barrier release broadcast to 8 per-group gen words (64 pollers
//      per cache line instead of 512).
// 17 barriers (was 23). All FMA/reduction orders identical to round-9.

#define DEV __device__ __forceinline__

static constexpr int VEC = 1280;
static constexpr int HID = 128;
static constexpr int BB  = 4;
static constexpr int SS  = 256;
static constexpr int NPART = 8;           // split-K partials (QK and FC1)
static constexpr long QK_PS = 262144;     // QK partial stride (1024*256)
static constexpr long H_PS  = 131072;     // FC1 partial stride (1024*128)
static constexpr int NBLK  = 512;         // persistent grid: 2 blocks/CU
static constexpr int NSPLIT_NONE = 1 << 30;

typedef float f32x4 __attribute__((ext_vector_type(4)));

struct Params {
  const float* X; const int* lys;
  const float* Wq[4]; const float* Wk[4]; const float* wv[4];
  const float* rW1[3]; const float* rb1[3]; const float* rW2[3]; const float* rb2[3];
  const float* hW1; const float* hb1; const float* hW2; const float* hb2;
  const float* hW3; const float* hb3;
  float* QKp[4]; float* Qd[4]; float* KT[4];   // per attention layer
  float* Yb[3]; float* Hp[3]; float* Xout[3];  // per layer 0..2
  float* out;
  // bar layout (u32): [g*32] 8 group arrive ctrs; [256] root;
  // [288+g*32] 8 per-group gen words; [1024+l*32] FC2 ticket ctrs.
  unsigned* bar;
};

// ---- bypass stores (agent-scope, straight to coherence point) -------------
DEV void stcc(float* p, float v) {
  union { float f; unsigned u; } c; c.f = v;
  __hip_atomic_store((unsigned*)p, c.u, __ATOMIC_RELAXED,
                     __HIP_MEMORY_SCOPE_AGENT);
}
DEV void stcc4(float* p, float x, float y, float z, float w) {
  f32x4 v; v[0] = x; v[1] = y; v[2] = z; v[3] = w;
  asm volatile("global_store_dwordx4 %0, %1, off sc0 sc1"
               :: "v"(p), "v"(v) : "memory");
}

DEV float ftanh(float x) {
  float e = __expf(2.0f * x);
  return 1.0f - __fdividef(2.0f, e + 1.0f);
}

DEV float waveSum(float v) {
#pragma unroll
  for (int off = 32; off > 0; off >>= 1) v += __shfl_xor(v, off, 64);
  return v;
}
DEV float waveMax(float v) {
#pragma unroll
  for (int off = 32; off > 0; off >>= 1) v = fmaxf(v, __shfl_xor(v, off, 64));
  return v;
}
// blockDim.x == 256 (4 waves) everywhere these are used.
DEV float blockSum(float v, float* red) {
  v = waveSum(v);
  int tid = threadIdx.x;
  if ((tid & 63) == 0) red[tid >> 6] = v;
  __syncthreads();
  float r = (red[0] + red[1]) + (red[2] + red[3]);
  __syncthreads();
  return r;
}
DEV float blockMax(float v, float* red) {
  v = waveMax(v);
  int tid = threadIdx.x;
  if ((tid & 63) == 0) red[tid >> 6] = v;
  __syncthreads();
  float r = fmaxf(fmaxf(red[0], red[1]), fmaxf(red[2], red[3]));
  __syncthreads();
  return r;
}

// Fence-free grid barrier. Arrive: 8 group ctrs -> root. Release: root
// finisher broadcasts to 8 per-group gen words (64 pollers/line).
DEV void gsync(unsigned* bar, unsigned target) {
  __syncthreads();  // each wave drains its own vmcnt before s_barrier
  if (threadIdx.x == 0) {
    asm volatile("s_waitcnt vmcnt(0)" ::: "memory");
    const int g = (int)(blockIdx.x >> 6);
    unsigned* grp  = bar + (g << 5);
    unsigned* root = bar + 256;
    unsigned c = __hip_atomic_fetch_add(grp, 1u, __ATOMIC_RELAXED,
                                        __HIP_MEMORY_SCOPE_AGENT);
    if (c + 1u == target * 64u) {
      unsigned r = __hip_atomic_fetch_add(root, 1u, __ATOMIC_RELAXED,
                                          __HIP_MEMORY_SCOPE_AGENT);
      if (r + 1u == target * 8u) {
#pragma unroll
        for (int i = 0; i < 8; ++i)
          __hip_atomic_store(bar + 288 + (i << 5), target, __ATOMIC_RELAXED,
                             __HIP_MEMORY_SCOPE_AGENT);
      }
    }
    unsigned* gen = bar + 288 + (g << 5);
    while (__hip_atomic_load(gen, __ATOMIC_RELAXED,
                             __HIP_MEMORY_SCOPE_AGENT) < target)
      __builtin_amdgcn_s_sleep(2);
  }
  __syncthreads();
}

// ---------------------------------------------------------------------------
// fp32 GEMM task, BMx64 tile (BM in {64,32}), BK=16, 256 threads, microtile
// (BM/16)x4. Non-AFUSE: 2-deep ping-pong register prefetch. AFUSE: depth-1.
// Loads cached (write-once buffers); C-stores bypass 16B.
// MODE==0: plain.  MODE==1: z = K-split slice (kChunk each), C += z*sCb.
// ---------------------------------------------------------------------------
template <int BM, int MODE, bool AFUSE, bool OBIAS, bool ORES>
DEV void gemm_task(int n0, int m0, int z,
                   const float* __restrict__ A, long aPart,
                   const float* __restrict__ B0, const float* __restrict__ B1,
                   int nSplitB, int ldB,
                   float* __restrict__ C, long sCb,
                   const float* __restrict__ aBias,
                   const float* __restrict__ oBias,
                   const float* __restrict__ res,
                   int N, int K, int kChunk) {
  constexpr int MR = BM / 16;        // rows per thread (4 or 2)
  constexpr int LDA = BM + 4;
  __shared__ float As[16][LDA];
  __shared__ float Bs[16][68];

  float* Cb = C + (MODE >= 1 ? (long)z * sCb : 0L);
  const float* Bsel;
  int nb;
  if (n0 < nSplitB) { Bsel = B0; nb = n0; } else { Bsel = B1; nb = n0 - nSplitB; }

  const int kBeg = (MODE == 1) ? z * kChunk : 0;
  const int kEnd = (MODE == 1) ? kBeg + kChunk : K;

  const int tid = threadIdx.x;
  const int tx = tid & 15, ty = tid >> 4;
  const int ar = tid / (16 / MR);          // A row 0..BM-1
  const int ac = (tid % (16 / MR)) * MR;   // A k-offset
  const int br = tid >> 4, bc = (tid & 15) << 2;  // B: k-row, col

  struct FA { float v[MR]; };

  auto loadA = [&](int kt) {
    FA r;
    const float* ap = A + (size_t)(m0 + ar) * K + kt + ac;
    if constexpr (MR == 4) {
      const float4 t = *(const float4*)ap;
      r.v[0] = t.x; r.v[1] = t.y; r.v[2] = t.z; r.v[3] = t.w;
    } else {
      const float2 t = *(const float2*)ap;
      r.v[0] = t.x; r.v[1] = t.y;
    }
    return r;
  };
  auto loadAF = [&](int kt) {  // AFUSE: sum NPART partials + bias + relu
    FA s;
#pragma unroll
    for (int q = 0; q < MR; ++q) s.v[q] = 0.0f;
    const size_t aoff = (size_t)(m0 + ar) * K + kt + ac;
#pragma unroll
    for (int p = 0; p < NPART; ++p) {
      const float* ap = A + (long)p * aPart + aoff;
      if constexpr (MR == 4) {
        const float4 t = *(const float4*)ap;
        s.v[0] += t.x; s.v[1] += t.y; s.v[2] += t.z; s.v[3] += t.w;
      } else {
        const float2 t = *(const float2*)ap;
        s.v[0] += t.x; s.v[1] += t.y;
      }
    }
#pragma unroll
    for (int q = 0; q < MR; ++q)
      s.v[q] = fmaxf(s.v[q] + aBias[kt + ac + q], 0.0f);
    return s;
  };
  auto loadBf = [&](int kt) -> float4 {
    return *(const float4*)(Bsel + (size_t)(kt + br) * ldB + nb + bc);
  };
  auto stAB = [&](const FA& a, const float4& b) {
#pragma unroll
    for (int q = 0; q < MR; ++q) As[ac + q][ar] = a.v[q];
    *(float4*)&Bs[br][bc] = b;
  };

  float acc[MR][4] = {};
  auto domath = [&]() {
#pragma unroll
    for (int kk = 0; kk < 16; ++kk) {
      float a[MR], b[4];
      if constexpr (MR == 4) {
        const float4 t = *(const float4*)&As[kk][ty << 2];
        a[0] = t.x; a[1] = t.y; a[2] = t.z; a[3] = t.w;
      } else {
        const float2 t = *(const float2*)&As[kk][ty << 1];
        a[0] = t.x; a[1] = t.y;
      }
      const float4 tb = *(const float4*)&Bs[kk][tx << 2];
      b[0] = tb.x; b[1] = tb.y; b[2] = tb.z; b[3] = tb.w;
#pragma unroll
      for (int i = 0; i < MR; ++i)
#pragma unroll
        for (int j = 0; j < 4; ++j) acc[i][j] = fmaf(a[i], b[j], acc[i][j]);
    }
  };

  if constexpr (!AFUSE) {
    FA aA = loadA(kBeg);
    float4 bA = loadBf(kBeg);
    FA aB = aA; float4 bB = bA;  // init only; unused unless >=2 tiles
    if (kBeg + 16 < kEnd) { aB = loadA(kBeg + 16); bB = loadBf(kBeg + 16); }
    for (int kt = kBeg; kt < kEnd; kt += 32) {
      __syncthreads();
      stAB(aA, bA);
      __syncthreads();
      if (kt + 32 < kEnd) { aA = loadA(kt + 32); bA = loadBf(kt + 32); }
      domath();
      if (kt + 16 < kEnd) {
        __syncthreads();
        stAB(aB, bB);
        __syncthreads();
        if (kt + 48 < kEnd) { aB = loadA(kt + 48); bB = loadBf(kt + 48); }
        domath();
      }
    }
  } else {
    FA a4 = loadAF(kBeg);
    float4 b4 = loadBf(kBeg);
    for (int kt = kBeg; kt < kEnd; kt += 16) {
      __syncthreads();
      stAB(a4, b4);
      __syncthreads();
      if (kt + 16 < kEnd) { a4 = loadAF(kt + 16); b4 = loadBf(kt + 16); }
      domath();
    }
  }

#pragma unroll
  for (int i = 0; i < MR; ++i) {
    const int m = m0 + ty * MR + i;
    const int n = n0 + (tx << 2);
    float o[4] = {acc[i][0], acc[i][1], acc[i][2], acc[i][3]};
    if (OBIAS) {
#pragma unroll
      for (int j = 0; j < 4; ++j) o[j] += oBias[n + j];
    }
    if (ORES) {
      const float4 r4 = *(const float4*)(res + (size_t)m * N + n);
      o[0] += r4.x; o[1] += r4.y; o[2] += r4.z; o[3] += r4.w;
    }
    stcc4(&Cb[(size_t)m * N + n], o[0], o[1], o[2], o[3]);
  }
}

// Reduce NPART QK partials row r (cols 0..127=Q, 128..255=K) into Qd + KT.
DEV void qksum_task(int r, const float* __restrict__ QKp,
                    float* __restrict__ Qd, float* __restrict__ KT) {
  const int tid = threadIdx.x;
  const int b = r >> 8, j = r & 255;
  const size_t off = (size_t)r * 256 + tid;
  float v = 0.0f;
#pragma unroll
  for (int p = 0; p < NPART; ++p) v += QKp[(long)p * QK_PS + off];
  if (tid < 128) {
    stcc(Qd + (size_t)r * 128 + tid, v);
  } else {
    stcc(KT + (size_t)b * 32768 + (size_t)(tid - 128) * 256 + j, v);
  }
}

// ---------------------------------------------------------------------------
// Fused scores+softmax+PV+LN for 2 q-rows. t in [0,512): b=t>>7, i0=(t&127)*2.
// attn rows live in LDS only; PV = 2 dot-rows vs Xin (j ascending, identical
// FMA order to the old PV GEMM); residual + LN identical ops; Yb written 16B.
// ---------------------------------------------------------------------------
DEV void spl_task(int t, const float* __restrict__ Qd,
                  const float* __restrict__ KT,
                  const float* __restrict__ wv,
                  const float* __restrict__ Xin,
                  float* __restrict__ Yb) {
  const int b = t >> 7, i0 = (t & 127) << 1, tid = threadIdx.x;
  __shared__ float qs[2][128], wvs[128], red[4], aws[2][256], xbuf[1280];
  {
    const int rr = tid >> 7, h = tid & 127;
    qs[rr][h] = Qd[(size_t)(b * 256 + i0 + rr) * 128 + h];
  }
  if (tid < 128) wvs[tid] = wv[tid];
  __syncthreads();

  const float* KTb = KT + (size_t)b * 32768 + tid;
  float s0 = 0.0f, s1 = 0.0f;
#pragma unroll 4
  for (int h = 0; h < 128; h += 4) {
    const float k0 = KTb[(h + 0) * 256];
    const float k1 = KTb[(h + 1) * 256];
    const float k2 = KTb[(h + 2) * 256];
    const float k3 = KTb[(h + 3) * 256];
    const float w0 = wvs[h], w1 = wvs[h + 1], w2 = wvs[h + 2], w3 = wvs[h + 3];
    s0 += w0 * ftanh(qs[0][h] + k0) + w1 * ftanh(qs[0][h + 1] + k1) +
          w2 * ftanh(qs[0][h + 2] + k2) + w3 * ftanh(qs[0][h + 3] + k3);
    s1 += w0 * ftanh(qs[1][h] + k0) + w1 * ftanh(qs[1][h + 1] + k1) +
          w2 * ftanh(qs[1][h + 2] + k2) + w3 * ftanh(qs[1][h + 3] + k3);
  }
  {
    const float mx = blockMax(s0, red);
    const float e = __expf(s0 - mx);
    const float tot = blockSum(e, red);
    aws[0][tid] = e / tot;
  }
  {
    const float mx = blockMax(s1, red);
    const float e = __expf(s1 - mx);
    const float tot = blockSum(e, red);
    aws[1][tid] = e / tot;
  }
  __syncthreads();

  // PV: both rows share the Xin[j,:] stream; j ascending (same order as the
  // old k-tiled GEMM). Thread owns cols {tid, tid+256, ..., tid+1024}.
  const float* Xb = Xin + (size_t)b * SS * VEC;
  float a0[5] = {}, a1[5] = {};
#pragma unroll 2
  for (int j = 0; j < 256; ++j) {
    const float w0 = aws[0][j], w1 = aws[1][j];
    const float* xr = Xb + (size_t)j * VEC + tid;
#pragma unroll
    for (int k = 0; k < 5; ++k) {
      const float x = xr[k * 256];
      a0[k] = fmaf(w0, x, a0[k]);
      a1[k] = fmaf(w1, x, a1[k]);
    }
  }

#pragma unroll
  for (int r = 0; r < 2; ++r) {
    const float* xres = Xb + (size_t)(i0 + r) * VEC + tid;
    float v[5];
    float sum = 0.0f;
#pragma unroll
    for (int k = 0; k < 5; ++k) {
      v[k] = (r ? a1[k] : a0[k]) + xres[k * 256];
      sum += v[k];
    }
    sum = blockSum(sum, red);
    const float m = sum * (1.0f / VEC);
    float sq = 0.0f;
#pragma unroll
    for (int k = 0; k < 5; ++k) {
      const float dl = v[k] - m;
      sq += dl * dl;
    }
    sq = blockSum(sq, red);
    const float rstd = rsqrtf(sq * (1.0f / VEC) + 1e-5f);
#pragma unroll
    for (int k = 0; k < 5; ++k) xbuf[tid + k * 256] = (v[k] - m) * rstd;
    __syncthreads();
    float* y = Yb + (size_t)(b * 256 + i0 + r) * VEC;
    {
      const float* x = xbuf + (tid << 2);
      stcc4(y + (tid << 2), x[0], x[1], x[2], x[3]);
    }
    if (tid < 64) {
      const float* x = xbuf + 1024 + (tid << 2);
      stcc4(y + 1024 + (tid << 2), x[0], x[1], x[2], x[3]);
    }
    __syncthreads();  // xbuf reused by row 1
  }
}

// Fused layer-4 tail for batch b: scores4 + pv4 + LN + head, all in-block.
DEV void tail_task(int b, const Params& p) {
  __shared__ float qs[128], wvs[128], red[4], aws[256];
  __shared__ float xrow[1280], partial[256];
  __shared__ float h1s[32], h2s[12];
  const int tid = threadIdx.x;
  const int lp = p.lys[0];
  const float* X3 = p.Xout[2];
  const float* Qd = p.Qd[3];
  const float* KT = p.KT[3];

  if (tid < 128) {
    qs[tid] = Qd[(size_t)(b * 256 + lp) * 128 + tid];
    wvs[tid] = p.wv[3][tid];
  }
  __syncthreads();
  const float* KTb = KT + (size_t)b * 32768 + tid;
  float s = 0.0f;
#pragma unroll 4
  for (int h = 0; h < 128; h += 4) {
    s += wvs[h + 0] * ftanh(qs[h + 0] + KTb[(h + 0) * 256]);
    s += wvs[h + 1] * ftanh(qs[h + 1] + KTb[(h + 1) * 256]);
    s += wvs[h + 2] * ftanh(qs[h + 2] + KTb[(h + 2) * 256]);
    s += wvs[h + 3] * ftanh(qs[h + 3] + KTb[(h + 3) * 256]);
  }
  const float mx = blockMax(s, red);
  const float e = __expf(s - mx);
  const float tot = blockSum(e, red);
  aws[tid] = e / tot;
  __syncthreads();

  const float* Xb = X3 + (size_t)b * SS * VEC;
  float v[5] = {};
#pragma unroll 2
  for (int j = 0; j < 256; ++j) {
    const float aw = aws[j];
    const float* xr = Xb + (size_t)j * VEC + tid;
#pragma unroll
    for (int k = 0; k < 5; ++k) v[k] = fmaf(aw, xr[k * 256], v[k]);
  }
#pragma unroll
  for (int k = 0; k < 5; ++k) v[k] += Xb[(size_t)lp * VEC + tid + k * 256];

  float sum = (v[0] + v[1]) + (v[2] + v[3]) + v[4];
  sum = blockSum(sum, red);
  const float m = sum * (1.0f / VEC);
  float sq = 0.0f;
#pragma unroll
  for (int k = 0; k < 5; ++k) {
    const float dl = v[k] - m;
    sq += dl * dl;
  }
  sq = blockSum(sq, red);
  const float rstd = rsqrtf(sq * (1.0f / VEC) + 1e-5f);
#pragma unroll
  for (int k = 0; k < 5; ++k) xrow[tid + k * 256] = (v[k] - m) * rstd;
  __syncthreads();

  {
    const int n = tid & 31, sl = tid >> 5;
    float pacc = 0.0f;
    for (int k = sl * 160; k < sl * 160 + 160; ++k)
      pacc = fmaf(xrow[k], p.hW1[(size_t)k * 32 + n], pacc);
    partial[tid] = pacc;
  }
  __syncthreads();
  if (tid < 32) {
    float t2 = 0.0f;
#pragma unroll
    for (int s2 = 0; s2 < 8; ++s2) t2 += partial[s2 * 32 + tid];
    h1s[tid] = fmaxf(t2 + p.hb1[tid], 0.0f);
  }
  __syncthreads();
  if (tid < 12) {
    float t2 = 0.0f;
#pragma unroll
    for (int k = 0; k < 32; ++k) t2 = fmaf(h1s[k], p.hW2[k * 12 + tid], t2);
    h2s[tid] = fmaxf(t2 + p.hb2[tid], 0.0f);
  }
  __syncthreads();
  if (tid < 2) {
    float t2 = 0.0f;
#pragma unroll
    for (int k = 0; k < 12; ++k) t2 = fmaf(h2s[k], p.hW3[k * 2 + tid], t2);
    p.out[b * 2 + tid] = t2 + p.hb3[tid];  // normal store: kernel-end release
  }
}

// ---------------------------------------------------------------------------
// Persistent kernel. 512 blocks x 256 threads, launch_bounds(256,2).
// LDS ~33KB, VGPR<=128 -> occupancy limit 4 blocks/CU > 2 requested (slack).
// ---------------------------------------------------------------------------
__global__ __launch_bounds__(256, 2) void mega_k(Params p) {
  __shared__ int tkt;
  const int bid = blockIdx.x;
  unsigned ph = 0;

  for (int l = 0; l < 4; ++l) {
    const float* Xin = (l == 0) ? p.X : p.Xout[l - 1];
    {  // QK projection: 4n x 16m x 8z = 512 tasks (1:1, balanced).
      const int x = bid & 3, y = (bid >> 2) & 15, z = bid >> 6;
      gemm_task<64, 1, false, false, false>(x * 64, y * 64, z, Xin, 0L,
          p.Wq[l], p.Wk[l], HID, HID, p.QKp[l], QK_PS,
          nullptr, nullptr, nullptr, 2 * HID, VEC, 160);
    }
    gsync(p.bar, ++ph);
    // Reduce partials -> dense Qd + transposed KT. 1024 rows / 512 blocks.
    qksum_task(bid, p.QKp[l], p.Qd[l], p.KT[l]);
    qksum_task(bid + NBLK, p.QKp[l], p.Qd[l], p.KT[l]);
    gsync(p.bar, ++ph);
    if (l == 3) break;
    // Fused scores+softmax+PV+LN: 512 tasks (1:1, balanced).
    spl_task(bid, p.Qd[l], p.KT[l], p.wv[l], Xin, p.Yb[l]);
    gsync(p.bar, ++ph);
    // FC1: Yb @ rW1 -> Hp. 2n x 32m x 8z = 512 tasks (1:1, balanced, BM=32).
    {
      const int x = bid & 1, y = (bid >> 1) & 31, z = bid >> 6;
      gemm_task<32, 1, false, false, false>(x * 64, y * 32, z, p.Yb[l], 0L,
          p.rW1[l], p.rW1[l], NSPLIT_NONE, HID, p.Hp[l], H_PS,
          nullptr, nullptr, nullptr, HID, VEC, 160);
    }
    gsync(p.bar, ++ph);
    // FC2: relu(sum Hp + b1) @ rW2 + b2 + Yb. 20n x 32m = 640 tasks, DYNAMIC.
    {
      unsigned* tick = p.bar + 1024 + (l << 5);
      for (;;) {
        if (threadIdx.x == 0)
          tkt = (int)__hip_atomic_fetch_add(tick, 1u, __ATOMIC_RELAXED,
                                            __HIP_MEMORY_SCOPE_AGENT);
        __syncthreads();
        const int t = tkt;
        if (t >= 640) break;
        const int x = t % 20, y = t / 20;
        gemm_task<32, 0, true, true, true>(x * 64, y * 32, 0, p.Hp[l], H_PS,
            p.rW2[l], p.rW2[l], NSPLIT_NONE, VEC, p.Xout[l], 0L,
            p.rb1[l], p.rb2[l], p.Yb[l], VEC, HID, 0);
      }
    }
    gsync(p.bar, ++ph);
  }
  // Layer-4 tail: one block per batch, fully fused.
  if (bid < BB) tail_task(bid, p);
}

__global__ void initbar_k(unsigned* __restrict__ bar) {
  const int tid = threadIdx.x;
  for (int i = tid; i < 2048; i += 256)
    __hip_atomic_store(bar + i, 0u, __ATOMIC_RELAXED,
                       __HIP_MEMORY_SCOPE_AGENT);
}

// ---------------------------------------------------------------------------
extern "C" void kernel_launch(void* const* d_in, const int* in_sizes, int n_in,
                              void* d_out, int out_size, void* d_ws, size_t ws_size,
                              hipStream_t stream) {
  Params p;
  p.X   = (const float*)d_in[0];
  p.lys = (const int*)d_in[1];
  p.Wq[0] = (const float*)d_in[2];  p.Wk[0] = (const float*)d_in[3];  p.wv[0] = (const float*)d_in[4];
  p.Wq[1] = (const float*)d_in[5];  p.Wk[1] = (const float*)d_in[6];  p.wv[1] = (const float*)d_in[7];
  p.Wq[2] = (const float*)d_in[8];  p.Wk[2] = (const float*)d_in[9];  p.wv[2] = (const float*)d_in[10];
  p.Wq[3] = (const float*)d_in[11]; p.Wk[3] = (const float*)d_in[12]; p.wv[3] = (const float*)d_in[13];
  p.rW1[0] = (const float*)d_in[14]; p.rb1[0] = (const float*)d_in[15];
  p.rW2[0] = (const float*)d_in[16]; p.rb2[0] = (const float*)d_in[17];
  p.rW1[1] = (const float*)d_in[18]; p.rb1[1] = (const float*)d_in[19];
  p.rW2[1] = (const float*)d_in[20]; p.rb2[1] = (const float*)d_in[21];
  p.rW1[2] = (const float*)d_in[22]; p.rb1[2] = (const float*)d_in[23];
  p.rW2[2] = (const float*)d_in[24]; p.rb2[2] = (const float*)d_in[25];
  p.hW1 = (const float*)d_in[26]; p.hb1 = (const float*)d_in[27];
  p.hW2 = (const float*)d_in[28]; p.hb2 = (const float*)d_in[29];
  p.hW3 = (const float*)d_in[30]; p.hb3 = (const float*)d_in[31];
  p.out = (float*)d_out;

  // Write-once versioned workspace (floats), ~78 MB (4KB-aligned buffers).
  float* w = (float*)d_ws;
  for (int l = 0; l < 4; ++l) { p.QKp[l] = w; w += (long)NPART * QK_PS; }  // 4 x 8MB
  for (int l = 0; l < 4; ++l) { p.Qd[l]  = w; w += 131072; }               // 4 x 0.5MB
  for (int l = 0; l < 4; ++l) { p.KT[l]  = w; w += 131072; }               // 4 x 0.5MB
  for (int l = 0; l < 3; ++l) { p.Yb[l]   = w; w += 1310720; }             // 3 x 5MB
  for (int l = 0; l < 3; ++l) { p.Hp[l]   = w; w += (long)NPART * H_PS; }  // 3 x 4MB
  for (int l = 0; l < 3; ++l) { p.Xout[l] = w; w += 1310720; }             // 3 x 5MB
  p.bar = (unsigned*)w;                                                    // 2048 u32

  initbar_k<<<dim3(1), dim3(256), 0, stream>>>(p.bar);
  mega_k<<<dim3(NBLK), dim3(256), 0, stream>>>(p);
}